// Round 1
// baseline (389.753 us; speedup 1.0000x reference)
//
#include <hip/hip_runtime.h>
#include <hip/hip_bf16.h>

#define GROUPS 12
#define POOL   64
#define TOPK   8
#define LAYERS 24
#define RANK   64
#define HID    1024
// per-pool-slot stride in weight_offset: [POOL, 2, HID*RANK*LAYERS]
#define D_LR   (HID * RANK * LAYERS)      // 1572864
#define POOL_STRIDE (2L * D_LR)           // 3145728

// ---------------- Phase 1: routing (one block, 768 threads) ----------------
// Computes mean cosine sim per pool slot, top-8, normalized weights.
// Deterministic: no float atomics; fixed summation order.
__global__ void routing_kernel(const float* __restrict__ q,     // [64, 768]
                               const float* __restrict__ keys,  // [12, 64, 64] (keys[0])
                               int* __restrict__ idx_out,       // [8]
                               float* __restrict__ w_out) {     // [8]
    __shared__ float invn[64][GROUPS];   // 1/||q[b,g,:]||
    __shared__ float qbar[GROUPS][64];   // sum_b qn[b,g,c]
    __shared__ float simg[GROUPS][64];   // sum_b sim[b,g,p]
    const int t = threadIdx.x;           // 0..767

    { // per-(b,g) query inverse norm
        int b = t / GROUPS, g = t % GROUPS;
        const float* row = q + b * 768 + g * 64;
        float ss = 0.f;
        #pragma unroll 8
        for (int c = 0; c < 64; ++c) { float v = row[c]; ss = fmaf(v, v, ss); }
        invn[b][g] = 1.f / fmaxf(sqrtf(ss), 1e-8f);
    }
    __syncthreads();
    { // qbar[g][c] = sum_b q[b,g,c] * invn[b][g]
        int g = t >> 6, c = t & 63;
        float s = 0.f;
        for (int b = 0; b < 64; ++b) s = fmaf(q[b * 768 + g * 64 + c], invn[b][g], s);
        qbar[g][c] = s;
    }
    __syncthreads();
    { // simg[g][p] = <qbar[g,:], keys[g,p,:]> / ||keys[g,p,:]||
        int g = t >> 6, p = t & 63;
        const float* krow = keys + (g * 64 + p) * 64;
        float ss = 0.f, dot = 0.f;
        #pragma unroll 8
        for (int c = 0; c < 64; ++c) {
            float v = krow[c];
            ss  = fmaf(v, v, ss);
            dot = fmaf(v, qbar[g][c], dot);
        }
        simg[g][p] = dot / fmaxf(sqrtf(ss), 1e-8f);
    }
    __syncthreads();
    if (t < 64) { // mean over (b,g): 768 samples
        float s = 0.f;
        for (int g = 0; g < GROUPS; ++g) s += simg[g][t];
        qbar[0][t] = s * (1.f / 768.f);
    }
    __syncthreads();
    if (t == 0) { // top-8 (ties -> lowest index, matching jax.lax.top_k), normalize
        float ms[POOL];
        for (int p = 0; p < POOL; ++p) ms[p] = qbar[0][p];
        float sum = 0.f;
        float vals[TOPK]; int ids[TOPK];
        for (int k = 0; k < TOPK; ++k) {
            float best = -3.4e38f; int bi = 0;
            for (int p = 0; p < POOL; ++p)
                if (ms[p] > best) { best = ms[p]; bi = p; }
            vals[k] = best; ids[k] = bi;
            ms[bi] = -3.4e38f; sum += best;
        }
        float inv = 1.f / (sum + 1e-9f);
        for (int k = 0; k < TOPK; ++k) { idx_out[k] = ids[k]; w_out[k] = vals[k] * inv; }
    }
}

// ---------------- Phase 2: 24 x [ C_l = (w*A_l)^T B_l ], K=512, M=N=1024 ----
// A[k][x] = weight_offset[idx[k/64], 0, l*65536 + (k%64)*1024 + x]  (x contiguous)
// B[k][y] = weight_offset[idx[k/64], 1, l*65536 + (k%64)*1024 + y]
// fp32 vector-ALU GEMM: 128x128 C-tile / block, 256 threads, 8x8 microtile, BK=16.
__global__ __launch_bounds__(256) void lowrank_gemm_kernel(
        const float* __restrict__ wo,   // [64, 2, D_LR]
        const int*   __restrict__ idx,  // [8]
        const float* __restrict__ w,    // [8]
        float*       __restrict__ out)  // [24, 1024, 1024]
{
    const int l  = blockIdx.z;
    const int m0 = blockIdx.y * 128;
    const int n0 = blockIdx.x * 128;

    __shared__ float As[16][128];
    __shared__ float Bs[16][128];
    __shared__ int   s_idx[TOPK];
    __shared__ float s_w[TOPK];

    const int tid = threadIdx.x;
    const int tx = tid & 15, ty = tid >> 4;

    if (tid < TOPK) { s_idx[tid] = idx[tid]; s_w[tid] = w[tid]; }
    __syncthreads();

    float acc[8][8];
    #pragma unroll
    for (int i = 0; i < 8; ++i)
        #pragma unroll
        for (int j = 0; j < 8; ++j) acc[i][j] = 0.f;

    for (int k0 = 0; k0 < 512; k0 += 16) {
        const int  n  = k0 >> 6;       // which top-k slot
        const int  r0 = k0 & 63;       // rank offset inside slot
        const long base = (long)s_idx[n] * POOL_STRIDE + (long)l * (RANK * HID) + (long)r0 * HID;
        const float wn = s_w[n];

        // stage 16x128 A (scaled by wn) and B tiles; 512 float4 loads, 2/thread
        #pragma unroll
        for (int p = 0; p < 2; ++p) {
            int v   = tid + p * 256;
            int row = v >> 5;          // 0..15
            int c4  = v & 31;          // 0..31 (float4 column)
            const float4 av = *(const float4*)(wo + base + (long)row * HID + m0 + c4 * 4);
            const float4 bv = *(const float4*)(wo + base + D_LR + (long)row * HID + n0 + c4 * 4);
            float4 aw = make_float4(wn * av.x, wn * av.y, wn * av.z, wn * av.w);
            *(float4*)&As[row][c4 * 4] = aw;
            *(float4*)&Bs[row][c4 * 4] = bv;
        }
        __syncthreads();

        #pragma unroll
        for (int k = 0; k < 16; ++k) {
            float af[8], bf[8];
            #pragma unroll
            for (int i = 0; i < 8; ++i) af[i] = As[k][i * 16 + ty];
            #pragma unroll
            for (int j = 0; j < 8; ++j) bf[j] = Bs[k][j * 16 + tx];
            #pragma unroll
            for (int i = 0; i < 8; ++i)
                #pragma unroll
                for (int j = 0; j < 8; ++j)
                    acc[i][j] = fmaf(af[i], bf[j], acc[i][j]);
        }
        __syncthreads();
    }

    float* o = out + (long)l * (1024 * 1024);
    #pragma unroll
    for (int i = 0; i < 8; ++i) {
        const int m = m0 + i * 16 + ty;
        #pragma unroll
        for (int j = 0; j < 8; ++j) {
            o[(long)m * 1024 + n0 + j * 16 + tx] = acc[i][j];
        }
    }
}

extern "C" void kernel_launch(void* const* d_in, const int* in_sizes, int n_in,
                              void* d_out, int out_size, void* d_ws, size_t ws_size,
                              hipStream_t stream) {
    const float* q    = (const float*)d_in[0];  // [64,768]
    const float* keys = (const float*)d_in[1];  // [1,12,64,64]
    const float* wo   = (const float*)d_in[2];  // [64,2,1572864]
    float* out = (float*)d_out;                 // [24,1024,1024]

    int*   idx = (int*)d_ws;
    float* w   = (float*)((char*)d_ws + 32);

    routing_kernel<<<1, 768, 0, stream>>>(q, keys, idx, w);

    dim3 grid(1024 / 128, 1024 / 128, LAYERS);  // (8, 8, 24)
    lowrank_gemm_kernel<<<grid, 256, 0, stream>>>(wo, idx, w, out);
}

// Round 2
// 109.120 us; speedup vs baseline: 3.5718x; 3.5718x over previous
//
#include <hip/hip_runtime.h>
#include <hip/hip_bf16.h>

#define GROUPS 12
#define POOL   64
#define TOPK   8
#define LAYERS 24
#define RANK   64
#define HID    1024
// weight_offset: [POOL, 2, HID*RANK*LAYERS]
#define D_LR   (HID * RANK * LAYERS)      // 1572864
#define POOL_STRIDE (2L * D_LR)           // 3145728

typedef __attribute__((ext_vector_type(8))) short bf16x8;
typedef __attribute__((ext_vector_type(4))) float f32x4;

__device__ __forceinline__ unsigned bfpack2(float lo, float hi) {
    float2 t; t.x = lo; t.y = hi;
    union { __hip_bfloat162 h; unsigned u; } cv;
    cv.h = __float22bfloat162_rn(t);
    return cv.u;
}

// ---------------- Phase 1: routing (one block, 768 threads) ----------------
__global__ void routing_kernel(const float* __restrict__ q,     // [64, 768]
                               const float* __restrict__ keys,  // [12, 64, 64]
                               int* __restrict__ idx_out,       // [8]
                               float* __restrict__ w_out) {     // [8]
    __shared__ float invn[64][GROUPS];
    __shared__ float qbar[GROUPS][64];
    __shared__ float simg[GROUPS][64];
    const int t = threadIdx.x;

    {
        int b = t / GROUPS, g = t % GROUPS;
        const float* row = q + b * 768 + g * 64;
        float ss = 0.f;
        #pragma unroll 8
        for (int c = 0; c < 64; ++c) { float v = row[c]; ss = fmaf(v, v, ss); }
        invn[b][g] = 1.f / fmaxf(sqrtf(ss), 1e-8f);
    }
    __syncthreads();
    {
        int g = t >> 6, c = t & 63;
        float s = 0.f;
        for (int b = 0; b < 64; ++b) s = fmaf(q[b * 768 + g * 64 + c], invn[b][g], s);
        qbar[g][c] = s;
    }
    __syncthreads();
    {
        int g = t >> 6, p = t & 63;
        const float* krow = keys + (g * 64 + p) * 64;
        float ss = 0.f, dot = 0.f;
        #pragma unroll 8
        for (int c = 0; c < 64; ++c) {
            float v = krow[c];
            ss  = fmaf(v, v, ss);
            dot = fmaf(v, qbar[g][c], dot);
        }
        simg[g][p] = dot / fmaxf(sqrtf(ss), 1e-8f);
    }
    __syncthreads();
    if (t < 64) {
        float s = 0.f;
        for (int g = 0; g < GROUPS; ++g) s += simg[g][t];
        qbar[0][t] = s * (1.f / 768.f);
    }
    __syncthreads();
    if (t == 0) {
        float ms[POOL];
        for (int p = 0; p < POOL; ++p) ms[p] = qbar[0][p];
        float sum = 0.f;
        float vals[TOPK]; int ids[TOPK];
        for (int k = 0; k < TOPK; ++k) {
            float best = -3.4e38f; int bi = 0;
            for (int p = 0; p < POOL; ++p)
                if (ms[p] > best) { best = ms[p]; bi = p; }
            vals[k] = best; ids[k] = bi;
            ms[bi] = -3.4e38f; sum += best;
        }
        float inv = 1.f / (sum + 1e-9f);
        for (int k = 0; k < TOPK; ++k) { idx_out[k] = ids[k]; w_out[k] = vals[k] * inv; }
    }
}

// ---------------- Phase 2: bf16 MFMA GEMM per layer ----------------
// C_l[m][n] = sum_s w_s * sum_r A[idx_s, l, r, m] * B[idx_s, l, r, n]
// 128x128 tile / block, 4 waves (2x2), BK=64 (= one slot), swizzled LDS,
// reg-staged fp32->bf16 transpose, async next-slot prefetch.
__global__ __launch_bounds__(256) void lowrank_mfma_kernel(
        const float* __restrict__ wo,   // [64, 2, D_LR]
        const int*   __restrict__ idx,  // [8]
        const float* __restrict__ w,    // [8]
        float*       __restrict__ out)  // [24, 1024, 1024]
{
    const int l  = blockIdx.z;
    const int m0 = blockIdx.y * 128;
    const int n0 = blockIdx.x * 128;

    // LDS tiles: [row(m or n)][8 chunks of 8 bf16 along K], XOR-swizzled chunks
    __shared__ uint4 As4[128][8];
    __shared__ uint4 Bs4[128][8];
    __shared__ int   s_idx[TOPK];
    __shared__ float s_w[TOPK];

    const int tid = threadIdx.x;
    if (tid < TOPK) { s_idx[tid] = idx[tid]; s_w[tid] = w[tid]; }
    __syncthreads();

    const int lane = tid & 63;
    const int wave = tid >> 6;
    const int wr = wave >> 1, wc = wave & 1;   // 2x2 wave grid, 64x64 per wave
    const int fr = lane & 15;                  // fragment row (m or n within 16)
    const int kb = lane >> 4;                  // k-block 0..3

    const int sm    = tid & 127;               // strip column (m for A, n for B)
    const int rhalf = tid >> 7;                // which 32 K-rows this thread stages
    const int cbase = rhalf * 4;               // first absolute chunk (of 8)

    f32x4 zero4 = {0.f, 0.f, 0.f, 0.f};
    f32x4 acc[4][4];
    #pragma unroll
    for (int i = 0; i < 4; ++i)
        #pragma unroll
        for (int j = 0; j < 4; ++j) acc[i][j] = zero4;

    uint4 sa[4], sb[4];

    auto load_cvt = [&](int s, uint4 (&oa)[4], uint4 (&ob)[4]) {
        const long base = (long)s_idx[s] * POOL_STRIDE + (long)l * (RANK * HID);
        const float wn = s_w[s];
        const float* pa = wo + base + (long)(rhalf * 32) * HID + (m0 + sm);
        const float* pb = wo + base + D_LR + (long)(rhalf * 32) * HID + (n0 + sm);
        float va[32], vb[32];
        #pragma unroll
        for (int j = 0; j < 32; ++j) va[j] = pa[(long)j * HID];
        #pragma unroll
        for (int j = 0; j < 32; ++j) vb[j] = pb[(long)j * HID];
        #pragma unroll
        for (int qq = 0; qq < 4; ++qq) {
            oa[qq].x = bfpack2(wn * va[qq*8+0], wn * va[qq*8+1]);
            oa[qq].y = bfpack2(wn * va[qq*8+2], wn * va[qq*8+3]);
            oa[qq].z = bfpack2(wn * va[qq*8+4], wn * va[qq*8+5]);
            oa[qq].w = bfpack2(wn * va[qq*8+6], wn * va[qq*8+7]);
            ob[qq].x = bfpack2(vb[qq*8+0], vb[qq*8+1]);
            ob[qq].y = bfpack2(vb[qq*8+2], vb[qq*8+3]);
            ob[qq].z = bfpack2(vb[qq*8+4], vb[qq*8+5]);
            ob[qq].w = bfpack2(vb[qq*8+6], vb[qq*8+7]);
        }
    };

    load_cvt(0, sa, sb);

    for (int s = 0; s < 8; ++s) {
        // swizzled LDS store: chunk' = chunk ^ (row & 7)
        #pragma unroll
        for (int qq = 0; qq < 4; ++qq) {
            const int cp = (cbase + qq) ^ (sm & 7);
            As4[sm][cp] = sa[qq];
            Bs4[sm][cp] = sb[qq];
        }
        __syncthreads();

        if (s < 7) load_cvt(s + 1, sa, sb);   // prefetch next slot under MFMA

        #pragma unroll
        for (int kk = 0; kk < 2; ++kk) {
            bf16x8 af[4], bfv[4];
            const int chunk = kk * 4 + kb;
            #pragma unroll
            for (int fi = 0; fi < 4; ++fi) {
                const int m = wr * 64 + fi * 16 + fr;
                af[fi] = *(const bf16x8*)&As4[m][chunk ^ (m & 7)];
            }
            #pragma unroll
            for (int fj = 0; fj < 4; ++fj) {
                const int n = wc * 64 + fj * 16 + fr;
                bfv[fj] = *(const bf16x8*)&Bs4[n][chunk ^ (n & 7)];
            }
            #pragma unroll
            for (int fi = 0; fi < 4; ++fi)
                #pragma unroll
                for (int fj = 0; fj < 4; ++fj)
                    acc[fi][fj] = __builtin_amdgcn_mfma_f32_16x16x32_bf16(
                        af[fi], bfv[fj], acc[fi][fj], 0, 0, 0);
        }
        __syncthreads();
    }

    // epilogue: C/D layout col = lane&15 (n), row = (lane>>4)*4 + reg (m)
    float* o = out + (long)l * (1024 * 1024);
    #pragma unroll
    for (int fi = 0; fi < 4; ++fi) {
        #pragma unroll
        for (int fj = 0; fj < 4; ++fj) {
            const int n = n0 + wc * 64 + fj * 16 + fr;
            #pragma unroll
            for (int v = 0; v < 4; ++v) {
                const int m = m0 + wr * 64 + fi * 16 + kb * 4 + v;
                o[(long)m * 1024 + n] = acc[fi][fj][v];
            }
        }
    }
}

extern "C" void kernel_launch(void* const* d_in, const int* in_sizes, int n_in,
                              void* d_out, int out_size, void* d_ws, size_t ws_size,
                              hipStream_t stream) {
    const float* q    = (const float*)d_in[0];  // [64,768]
    const float* keys = (const float*)d_in[1];  // [1,12,64,64]
    const float* wo   = (const float*)d_in[2];  // [64,2,1572864]
    float* out = (float*)d_out;                 // [24,1024,1024]

    int*   idx = (int*)d_ws;
    float* w   = (float*)((char*)d_ws + 32);

    routing_kernel<<<1, 768, 0, stream>>>(q, keys, idx, w);

    dim3 grid(1024 / 128, 1024 / 128, LAYERS);  // (n, m, layer)
    lowrank_mfma_kernel<<<grid, 256, 0, stream>>>(wo, idx, w, out);
}

// Round 3
// 82.957 us; speedup vs baseline: 4.6983x; 1.3154x over previous
//
#include <hip/hip_runtime.h>
#include <hip/hip_bf16.h>

#define GROUPS 12
#define POOL   64
#define TOPK   8
#define LAYERS 24
#define RANK   64
#define HID    1024
// weight_offset: [POOL, 2, HID*RANK*LAYERS]
#define D_LR   (HID * RANK * LAYERS)      // 1572864
#define POOL_STRIDE (2L * D_LR)           // 3145728

typedef __attribute__((ext_vector_type(8))) short bf16x8;
typedef __attribute__((ext_vector_type(4))) float f32x4;

__device__ __forceinline__ unsigned bfpack2(float lo, float hi) {
    float2 t; t.x = lo; t.y = hi;
    union { __hip_bfloat162 h; unsigned u; } cv;
    cv.h = __float22bfloat162_rn(t);
    return cv.u;
}

// swizzled chunk index: balanced for both write (col=4*lane+cc, chunk fixed)
// and read (col=base+lane&15, chunk=kk*4+lane>>4) 8-lane bank phases
__device__ __forceinline__ int sw_idx(int col, int chunk) {
    return chunk ^ (col & 7) ^ ((col >> 2) & 7);
}

// ---------------- Phase 1: routing (one block, 768 threads) ----------------
__global__ void routing_kernel(const float* __restrict__ q,     // [64, 768]
                               const float* __restrict__ keys,  // [12, 64, 64]
                               int* __restrict__ idx_out,       // [8]
                               float* __restrict__ w_out) {     // [8]
    __shared__ float invn[64][GROUPS];
    __shared__ float qbar[GROUPS][64];
    __shared__ float simg[GROUPS][64];
    const int t = threadIdx.x;

    {
        int b = t / GROUPS, g = t % GROUPS;
        const float* row = q + b * 768 + g * 64;
        float ss = 0.f;
        #pragma unroll 8
        for (int c = 0; c < 64; ++c) { float v = row[c]; ss = fmaf(v, v, ss); }
        invn[b][g] = 1.f / fmaxf(sqrtf(ss), 1e-8f);
    }
    __syncthreads();
    {
        int g = t >> 6, c = t & 63;
        float s = 0.f;
        for (int b = 0; b < 64; ++b) s = fmaf(q[b * 768 + g * 64 + c], invn[b][g], s);
        qbar[g][c] = s;
    }
    __syncthreads();
    {
        int g = t >> 6, p = t & 63;
        const float* krow = keys + (g * 64 + p) * 64;
        float ss = 0.f, dot = 0.f;
        #pragma unroll 8
        for (int c = 0; c < 64; ++c) {
            float v = krow[c];
            ss  = fmaf(v, v, ss);
            dot = fmaf(v, qbar[g][c], dot);
        }
        simg[g][p] = dot / fmaxf(sqrtf(ss), 1e-8f);
    }
    __syncthreads();
    if (t < 64) {
        float s = 0.f;
        for (int g = 0; g < GROUPS; ++g) s += simg[g][t];
        qbar[0][t] = s * (1.f / 768.f);
    }
    __syncthreads();
    if (t == 0) {
        float ms[POOL];
        for (int p = 0; p < POOL; ++p) ms[p] = qbar[0][p];
        float sum = 0.f;
        float vals[TOPK]; int ids[TOPK];
        for (int k = 0; k < TOPK; ++k) {
            float best = -3.4e38f; int bi = 0;
            for (int p = 0; p < POOL; ++p)
                if (ms[p] > best) { best = ms[p]; bi = p; }
            vals[k] = best; ids[k] = bi;
            ms[bi] = -3.4e38f; sum += best;
        }
        float inv = 1.f / (sum + 1e-9f);
        for (int k = 0; k < TOPK; ++k) { idx_out[k] = ids[k]; w_out[k] = vals[k] * inv; }
    }
}

// ---------------- Phase 2: bf16 MFMA GEMM, 256x256 tile, 8 waves ----------------
// C_l[m][n] = sum_s w_s sum_r A[idx_s,l,r,m] B[idx_s,l,r,n]; BK = 64 (one slot).
// float4 global loads + in-register fp32->bf16 K-transpose (cvt_pk pairing),
// both-sides-balanced XOR swizzle, next-slot prefetch under MFMA.
__global__ __launch_bounds__(512, 2) void lowrank_mfma_kernel(
        const float* __restrict__ wo,   // [64, 2, D_LR]
        const int*   __restrict__ idx,  // [8]
        const float* __restrict__ w,    // [8]
        float*       __restrict__ out)  // [24, 1024, 1024]
{
    __shared__ uint4 As4[256][8];   // [col][K-chunk of 8 bf16], swizzled
    __shared__ uint4 Bs4[256][8];
    __shared__ int   s_idx[TOPK];
    __shared__ float s_w[TOPK];

    const int tid = threadIdx.x;
    // bijective chunked XCD map: dispatch d -> orig tile, 48 consecutive tiles
    // (3 layers) per XCD assuming round-robin d%8 placement
    const int d    = blockIdx.x;
    const int orig = (d & 7) * 48 + (d >> 3);
    const int l    = orig >> 4;
    const int rem  = orig & 15;
    const int m0   = (rem >> 2) * 256;
    const int n0   = (rem & 3) * 256;

    if (tid < TOPK) { s_idx[tid] = idx[tid]; s_w[tid] = w[tid]; }
    __syncthreads();

    const int lane = tid & 63;
    const int wave = tid >> 6;
    const int wr = wave >> 2;      // 0..1 : 128-row band
    const int wc = wave & 3;       // 0..3 : 64-col band
    const int fr = lane & 15;
    const int kb = lane >> 4;

    const int c4 = lane;           // column quad 0..63 (4 cols each)
    const int rg = wave;           // K-row octet 0..7

    f32x4 acc[8][4];
    #pragma unroll
    for (int i = 0; i < 8; ++i)
        #pragma unroll
        for (int j = 0; j < 4; ++j) acc[i][j] = (f32x4){0.f, 0.f, 0.f, 0.f};

    f32x4 araw[8], braw[8];

    auto load_raw = [&](int s) {
        const long base = (long)s_idx[s] * POOL_STRIDE + (long)l * (RANK * HID);
        const float* pa = wo + base + (long)(rg * 8) * HID + (m0 + c4 * 4);
        const float* pb = wo + base + D_LR + (long)(rg * 8) * HID + (n0 + c4 * 4);
        #pragma unroll
        for (int j = 0; j < 8; ++j) araw[j] = *(const f32x4*)(pa + (long)j * HID);
        #pragma unroll
        for (int j = 0; j < 8; ++j) braw[j] = *(const f32x4*)(pb + (long)j * HID);
    };

    load_raw(0);

    for (int s = 0; s < 8; ++s) {
        const float wn = s_w[s];
        // pack: 8 K-rows x 4 cols -> 4 K-contiguous bf16x8 chunks (free transpose)
        #pragma unroll
        for (int cc = 0; cc < 4; ++cc) {
            const int col = c4 * 4 + cc;
            uint4 ua, ub;
            ua.x = bfpack2(wn * araw[0][cc], wn * araw[1][cc]);
            ua.y = bfpack2(wn * araw[2][cc], wn * araw[3][cc]);
            ua.z = bfpack2(wn * araw[4][cc], wn * araw[5][cc]);
            ua.w = bfpack2(wn * araw[6][cc], wn * araw[7][cc]);
            ub.x = bfpack2(braw[0][cc], braw[1][cc]);
            ub.y = bfpack2(braw[2][cc], braw[3][cc]);
            ub.z = bfpack2(braw[4][cc], braw[5][cc]);
            ub.w = bfpack2(braw[6][cc], braw[7][cc]);
            const int cp = sw_idx(col, rg);
            As4[col][cp] = ua;
            Bs4[col][cp] = ub;
        }
        __syncthreads();

        if (s < 7) load_raw(s + 1);   // VMEM issue overlaps MFMA cluster

        #pragma unroll
        for (int kk = 0; kk < 2; ++kk) {
            const int chunk = kk * 4 + kb;
            bf16x8 bfv[4];
            #pragma unroll
            for (int fj = 0; fj < 4; ++fj) {
                const int n = wc * 64 + fj * 16 + fr;
                bfv[fj] = *(const bf16x8*)&Bs4[n][sw_idx(n, chunk)];
            }
            #pragma unroll
            for (int fi = 0; fi < 8; ++fi) {
                const int m = wr * 128 + fi * 16 + fr;
                const bf16x8 af = *(const bf16x8*)&As4[m][sw_idx(m, chunk)];
                #pragma unroll
                for (int fj = 0; fj < 4; ++fj)
                    acc[fi][fj] = __builtin_amdgcn_mfma_f32_16x16x32_bf16(
                        af, bfv[fj], acc[fi][fj], 0, 0, 0);
            }
        }
        __syncthreads();
    }

    // epilogue: C/D layout n = lane&15, m = (lane>>4)*4 + v (validated round 1)
    float* o = out + (long)l * (1024 * 1024);
    #pragma unroll
    for (int fi = 0; fi < 8; ++fi) {
        #pragma unroll
        for (int fj = 0; fj < 4; ++fj) {
            const int n = n0 + wc * 64 + fj * 16 + fr;
            #pragma unroll
            for (int v = 0; v < 4; ++v) {
                const int m = m0 + wr * 128 + fi * 16 + kb * 4 + v;
                o[(long)m * 1024 + n] = acc[fi][fj][v];
            }
        }
    }
}

extern "C" void kernel_launch(void* const* d_in, const int* in_sizes, int n_in,
                              void* d_out, int out_size, void* d_ws, size_t ws_size,
                              hipStream_t stream) {
    const float* q    = (const float*)d_in[0];  // [64,768]
    const float* keys = (const float*)d_in[1];  // [1,12,64,64]
    const float* wo   = (const float*)d_in[2];  // [64,2,1572864]
    float* out = (float*)d_out;                 // [24,1024,1024]

    int*   idx = (int*)d_ws;
    float* w   = (float*)((char*)d_ws + 32);

    routing_kernel<<<1, 768, 0, stream>>>(q, keys, idx, w);

    lowrank_mfma_kernel<<<dim3(384, 1, 1), 512, 0, stream>>>(wo, idx, w, out);
}